// Round 1
// baseline (64.209 us; speedup 1.0000x reference)
//
#include <hip/hip_runtime.h>
#include <math.h>

// 4 qubits, DIM=16. wire w <-> bit mask (8 >> w)  [wire 0 = MSB].
// All loops fully unrolled with compile-time indices so re[]/im[] live in VGPRs.

template<int S>
__device__ __forceinline__ void ry_c(float* re, float* im, float c, float s) {
#pragma unroll
    for (int i = 0; i < 16; ++i) {
        if ((i & S) == 0) {
            const int j = i | S;
            float ra = re[i], ia = im[i], rb = re[j], ib = im[j];
            re[i] = c * ra - s * rb;  im[i] = c * ia - s * ib;
            re[j] = s * ra + c * rb;  im[j] = s * ia + c * ib;
        }
    }
}

template<int S>
__device__ __forceinline__ void rx_c(float* re, float* im, float c, float s) {
#pragma unroll
    for (int i = 0; i < 16; ++i) {
        if ((i & S) == 0) {
            const int j = i | S;
            float ra = re[i], ia = im[i], rb = re[j], ib = im[j];
            // a' = c*a - i*s*b ; b' = -i*s*a + c*b
            re[i] = c * ra + s * ib;  im[i] = c * ia - s * rb;
            re[j] = c * rb + s * ia;  im[j] = c * ib - s * ra;
        }
    }
}

template<int S>
__device__ __forceinline__ void rz_c(float* re, float* im, float c, float s) {
#pragma unroll
    for (int i = 0; i < 16; ++i) {
        if ((i & S) == 0) {
            const int j = i | S;
            float ra = re[i], ia = im[i], rb = re[j], ib = im[j];
            // a' = e^{-i t/2} a ; b' = e^{+i t/2} b
            re[i] = c * ra + s * ia;  im[i] = c * ia - s * ra;
            re[j] = c * rb - s * ib;  im[j] = c * ib + s * rb;
        }
    }
}

template<int CM, int TM>
__device__ __forceinline__ void cnot_c(float* re, float* im) {
#pragma unroll
    for (int i = 0; i < 16; ++i) {
        if ((i & CM) != 0 && (i & TM) == 0) {
            const int j = i | TM;
            float t;
            t = re[i]; re[i] = re[j]; re[j] = t;
            t = im[i]; im[i] = im[j]; im[j] = t;
        }
    }
}

// One quanv patch: |0000> -> RY(p[w]) each wire -> fixed qp gate sequence -> <Z_w>.
__device__ __forceinline__ void quanv_sim(const float p[4],
                                          const float cq[6], const float sq[6],
                                          float meas[4]) {
    float cw[4], sw[4];
#pragma unroll
    for (int w = 0; w < 4; ++w) sincosf(0.5f * p[w], &sw[w], &cw[w]);

    float re[16], im[16];
#pragma unroll
    for (int i = 0; i < 16; ++i) {
        float v = (i & 8) ? sw[0] : cw[0];
        v *= (i & 4) ? sw[1] : cw[1];
        v *= (i & 2) ? sw[2] : cw[2];
        v *= (i & 1) ? sw[3] : cw[3];
        re[i] = v; im[i] = 0.0f;
    }

    rx_c<8>(re, im, cq[0], sq[0]);   // RX(qp0) wire 0
    ry_c<4>(re, im, cq[1], sq[1]);   // RY(qp1) wire 1
    rz_c<2>(re, im, cq[2], sq[2]);   // RZ(qp2) wire 2
    cnot_c<8, 4>(re, im);            // CNOT(0,1)
    ry_c<1>(re, im, cq[3], sq[3]);   // RY(qp3) wire 3
    cnot_c<2, 1>(re, im);            // CNOT(2,3)
    rx_c<4>(re, im, cq[4], sq[4]);   // RX(qp4) wire 1
    rz_c<1>(re, im, cq[5], sq[5]);   // RZ(qp5) wire 3

    float pr[16];
#pragma unroll
    for (int i = 0; i < 16; ++i) pr[i] = re[i] * re[i] + im[i] * im[i];
#pragma unroll
    for (int w = 0; w < 4; ++w) {
        const int mask = 8 >> w;
        float acc = 0.0f;
#pragma unroll
        for (int i = 0; i < 16; ++i) acc += (i & mask) ? -pr[i] : pr[i];
        meas[w] = acc;
    }
}

template<int S>
__device__ __forceinline__ void ry_r(float* re, float c, float s) {
#pragma unroll
    for (int i = 0; i < 16; ++i) {
        if ((i & S) == 0) {
            const int j = i | S;
            float ra = re[i], rb = re[j];
            re[i] = c * ra - s * rb;
            re[j] = s * ra + c * rb;
        }
    }
}

__device__ __forceinline__ void cz_chain(float* re) {
    // CZ(0,1)*CZ(1,2)*CZ(2,3): sign = (-1)^(n01+n12+n23)
#pragma unroll
    for (int i = 0; i < 16; ++i) {
        int f = (((i & 12) == 12) ? 1 : 0) ^ (((i & 6) == 6) ? 1 : 0) ^
                (((i & 3) == 3) ? 1 : 0);
        if (f) re[i] = -re[i];
    }
}

// Classifier circuit: RY layer (th0..3) -> CZ chain -> RY layer (th4..7) -> CZ chain.
// State stays real (RY + CZ only).
__device__ __forceinline__ void classifier_sim(const float th[8], float expv[4]) {
    float c0[4], s0[4];
#pragma unroll
    for (int q = 0; q < 4; ++q) sincosf(0.5f * th[q], &s0[q], &c0[q]);

    float re[16];
#pragma unroll
    for (int i = 0; i < 16; ++i) {
        float v = (i & 8) ? s0[0] : c0[0];
        v *= (i & 4) ? s0[1] : c0[1];
        v *= (i & 2) ? s0[2] : c0[2];
        v *= (i & 1) ? s0[3] : c0[3];
        re[i] = v;
    }
    cz_chain(re);

    float c1[4], s1[4];
#pragma unroll
    for (int q = 0; q < 4; ++q) sincosf(0.5f * th[4 + q], &s1[q], &c1[q]);
    ry_r<8>(re, c1[0], s1[0]);
    ry_r<4>(re, c1[1], s1[1]);
    ry_r<2>(re, c1[2], s1[2]);
    ry_r<1>(re, c1[3], s1[3]);
    cz_chain(re);

    float pr[16];
#pragma unroll
    for (int i = 0; i < 16; ++i) pr[i] = re[i] * re[i];
#pragma unroll
    for (int w = 0; w < 4; ++w) {
        const int mask = 8 >> w;
        float acc = 0.0f;
#pragma unroll
        for (int i = 0; i < 16; ++i) acc += (i & mask) ? -pr[i] : pr[i];
        expv[w] = acc;
    }
}

__global__ __launch_bounds__(64)
void quanv_hybrid_kernel(const float* __restrict__ x,
                         const float* __restrict__ qp,
                         const float* __restrict__ W,      // (10,4)
                         const float* __restrict__ bias,   // (10,)
                         float* __restrict__ out,          // (B,10)
                         int B) {
    const int b = blockIdx.x * blockDim.x + threadIdx.x;
    if (b >= B) return;

    // Only patches 0 and 1 of each image reach the output:
    // patch0 = x[b,0,0:2] + x[b,1,0:2]; patch1 = x[b,0,2:4] + x[b,1,2:4].
    // b*784 and b*784+28 are float4-aligned (784%4==0, 28%4==0).
    const float4* x4 = (const float4*)x;
    const float4 r0 = x4[b * 196];       // x[b,0,0..3]
    const float4 r1 = x4[b * 196 + 7];   // x[b,1,0..3]
    const float patch0[4] = {r0.x, r0.y, r1.x, r1.y};
    const float patch1[4] = {r0.z, r0.w, r1.z, r1.w};

    float cq[6], sq[6];
#pragma unroll
    for (int i = 0; i < 6; ++i) sincosf(0.5f * qp[i], &sq[i], &cq[i]);

    float th[8];
    quanv_sim(patch0, cq, sq, th);
    quanv_sim(patch1, cq, sq, th + 4);

    float expv[4];
    classifier_sim(th, expv);

    float logits[10];
#pragma unroll
    for (int k = 0; k < 10; ++k) {
        float acc = bias[k];
#pragma unroll
        for (int j = 0; j < 4; ++j) acc += expv[j] * W[k * 4 + j];
        logits[k] = acc;
    }
    float m = logits[0];
#pragma unroll
    for (int k = 1; k < 10; ++k) m = fmaxf(m, logits[k]);
    float sum = 0.0f;
#pragma unroll
    for (int k = 0; k < 10; ++k) sum += expf(logits[k] - m);
    const float lse = m + logf(sum);

    float* o = out + (size_t)b * 10;
#pragma unroll
    for (int k = 0; k < 10; ++k) o[k] = logits[k] - lse;
}

extern "C" void kernel_launch(void* const* d_in, const int* in_sizes, int n_in,
                              void* d_out, int out_size, void* d_ws, size_t ws_size,
                              hipStream_t stream) {
    const float* x    = (const float*)d_in[0];   // (B,28,28)
    const float* qp   = (const float*)d_in[1];   // (6,)
    const float* W    = (const float*)d_in[2];   // (10,4)
    const float* bias = (const float*)d_in[3];   // (10,)
    float* out = (float*)d_out;                  // (B,10)

    const int B = in_sizes[0] / 784;
    const int block = 64;
    const int grid = (B + block - 1) / block;
    quanv_hybrid_kernel<<<grid, block, 0, stream>>>(x, qp, W, bias, out, B);
}

// Round 2
// 61.683 us; speedup vs baseline: 1.0410x; 1.0410x over previous
//
#include <hip/hip_runtime.h>
#include <math.h>

// 4 qubits, DIM=16. wire w <-> bit mask (8 >> w)  [wire 0 = MSB].
// Fully unrolled so re[]/im[] stay in VGPRs. Native transcendentals
// (__sincosf/__expf/__logf): args are O(1), error ~1e-6 vs 5e-2 threshold.

template<int S>
__device__ __forceinline__ void ry_c(float* re, float* im, float c, float s) {
#pragma unroll
    for (int i = 0; i < 16; ++i) {
        if ((i & S) == 0) {
            const int j = i | S;
            float ra = re[i], ia = im[i], rb = re[j], ib = im[j];
            re[i] = c * ra - s * rb;  im[i] = c * ia - s * ib;
            re[j] = s * ra + c * rb;  im[j] = s * ia + c * ib;
        }
    }
}

template<int S>
__device__ __forceinline__ void rx_c(float* re, float* im, float c, float s) {
#pragma unroll
    for (int i = 0; i < 16; ++i) {
        if ((i & S) == 0) {
            const int j = i | S;
            float ra = re[i], ia = im[i], rb = re[j], ib = im[j];
            // a' = c*a - i*s*b ; b' = -i*s*a + c*b
            re[i] = c * ra + s * ib;  im[i] = c * ia - s * rb;
            re[j] = c * rb + s * ia;  im[j] = c * ib - s * ra;
        }
    }
}

template<int S>
__device__ __forceinline__ void rz_c(float* re, float* im, float c, float s) {
#pragma unroll
    for (int i = 0; i < 16; ++i) {
        if ((i & S) == 0) {
            const int j = i | S;
            float ra = re[i], ia = im[i], rb = re[j], ib = im[j];
            // a' = e^{-i t/2} a ; b' = e^{+i t/2} b
            re[i] = c * ra + s * ia;  im[i] = c * ia - s * ra;
            re[j] = c * rb - s * ib;  im[j] = c * ib + s * rb;
        }
    }
}

template<int CM, int TM>
__device__ __forceinline__ void cnot_c(float* re, float* im) {
#pragma unroll
    for (int i = 0; i < 16; ++i) {
        if ((i & CM) != 0 && (i & TM) == 0) {
            const int j = i | TM;
            float t;
            t = re[i]; re[i] = re[j]; re[j] = t;
            t = im[i]; im[i] = im[j]; im[j] = t;
        }
    }
}

// One quanv patch: |0000> -> RY(p[w]) each wire -> fixed qp sequence -> <Z_w>.
__device__ __forceinline__ void quanv_sim(const float p[4],
                                          const float cq[6], const float sq[6],
                                          float meas[4]) {
    float cw[4], sw[4];
#pragma unroll
    for (int w = 0; w < 4; ++w) __sincosf(0.5f * p[w], &sw[w], &cw[w]);

    float re[16], im[16];
#pragma unroll
    for (int i = 0; i < 16; ++i) {
        float v = (i & 8) ? sw[0] : cw[0];
        v *= (i & 4) ? sw[1] : cw[1];
        v *= (i & 2) ? sw[2] : cw[2];
        v *= (i & 1) ? sw[3] : cw[3];
        re[i] = v; im[i] = 0.0f;
    }

    rx_c<8>(re, im, cq[0], sq[0]);   // RX(qp0) wire 0
    ry_c<4>(re, im, cq[1], sq[1]);   // RY(qp1) wire 1
    rz_c<2>(re, im, cq[2], sq[2]);   // RZ(qp2) wire 2
    cnot_c<8, 4>(re, im);            // CNOT(0,1)
    ry_c<1>(re, im, cq[3], sq[3]);   // RY(qp3) wire 3
    cnot_c<2, 1>(re, im);            // CNOT(2,3)
    rx_c<4>(re, im, cq[4], sq[4]);   // RX(qp4) wire 1
    rz_c<1>(re, im, cq[5], sq[5]);   // RZ(qp5) wire 3

    float pr[16];
#pragma unroll
    for (int i = 0; i < 16; ++i) pr[i] = re[i] * re[i] + im[i] * im[i];
#pragma unroll
    for (int w = 0; w < 4; ++w) {
        const int mask = 8 >> w;
        float acc = 0.0f;
#pragma unroll
        for (int i = 0; i < 16; ++i) acc += (i & mask) ? -pr[i] : pr[i];
        meas[w] = acc;
    }
}

template<int S>
__device__ __forceinline__ void ry_r(float* re, float c, float s) {
#pragma unroll
    for (int i = 0; i < 16; ++i) {
        if ((i & S) == 0) {
            const int j = i | S;
            float ra = re[i], rb = re[j];
            re[i] = c * ra - s * rb;
            re[j] = s * ra + c * rb;
        }
    }
}

__device__ __forceinline__ void cz_chain(float* re) {
    // CZ(0,1)*CZ(1,2)*CZ(2,3): sign = (-1)^(n01+n12+n23)
#pragma unroll
    for (int i = 0; i < 16; ++i) {
        int f = (((i & 12) == 12) ? 1 : 0) ^ (((i & 6) == 6) ? 1 : 0) ^
                (((i & 3) == 3) ? 1 : 0);
        if (f) re[i] = -re[i];
    }
}

// Classifier: RY layer (th0..3) -> CZ chain -> RY layer (th4..7) -> CZ chain.
// State stays real (RY + CZ only).
__device__ __forceinline__ void classifier_sim(const float th[8], float expv[4]) {
    float c0[4], s0[4];
#pragma unroll
    for (int q = 0; q < 4; ++q) __sincosf(0.5f * th[q], &s0[q], &c0[q]);

    float re[16];
#pragma unroll
    for (int i = 0; i < 16; ++i) {
        float v = (i & 8) ? s0[0] : c0[0];
        v *= (i & 4) ? s0[1] : c0[1];
        v *= (i & 2) ? s0[2] : c0[2];
        v *= (i & 1) ? s0[3] : c0[3];
        re[i] = v;
    }
    cz_chain(re);

    float c1[4], s1[4];
#pragma unroll
    for (int q = 0; q < 4; ++q) __sincosf(0.5f * th[4 + q], &s1[q], &c1[q]);
    ry_r<8>(re, c1[0], s1[0]);
    ry_r<4>(re, c1[1], s1[1]);
    ry_r<2>(re, c1[2], s1[2]);
    ry_r<1>(re, c1[3], s1[3]);
    cz_chain(re);

    float pr[16];
#pragma unroll
    for (int i = 0; i < 16; ++i) pr[i] = re[i] * re[i];
#pragma unroll
    for (int w = 0; w < 4; ++w) {
        const int mask = 8 >> w;
        float acc = 0.0f;
#pragma unroll
        for (int i = 0; i < 16; ++i) acc += (i & mask) ? -pr[i] : pr[i];
        expv[w] = acc;
    }
}

// Lane pair (2b, 2b+1) handles image b: each lane simulates one patch,
// exchanges <Z> via shfl_xor, both (redundantly, lockstep-free) run the
// classifier, each lane writes 5 of the 10 outputs.
__global__ __launch_bounds__(256)
void quanv_hybrid_kernel(const float* __restrict__ x,
                         const float* __restrict__ qp,
                         const float* __restrict__ W,      // (10,4)
                         const float* __restrict__ bias,   // (10,)
                         float* __restrict__ out,          // (B,10)
                         int B) {
    const int tid = blockIdx.x * blockDim.x + threadIdx.x;
    const int b = tid >> 1;
    const int p = tid & 1;
    if (b >= B) return;

    // Only patches 0 and 1 of each image reach the output:
    // patch0 = {x[b,0,0:2], x[b,1,0:2]}; patch1 = {x[b,0,2:4], x[b,1,2:4]}.
    const float4* x4 = (const float4*)x;
    const float4 r0 = x4[b * 196];       // x[b,0,0..3]
    const float4 r1 = x4[b * 196 + 7];   // x[b,1,0..3]
    float patch[4];
    if (p == 0) { patch[0] = r0.x; patch[1] = r0.y; patch[2] = r1.x; patch[3] = r1.y; }
    else        { patch[0] = r0.z; patch[1] = r0.w; patch[2] = r1.z; patch[3] = r1.w; }

    float cq[6], sq[6];
#pragma unroll
    for (int i = 0; i < 6; ++i) __sincosf(0.5f * qp[i], &sq[i], &cq[i]);

    float thm[4];
    quanv_sim(patch, cq, sq, thm);

    float th[8];
#pragma unroll
    for (int j = 0; j < 4; ++j) {
        const float o = __shfl_xor(thm[j], 1);
        th[j]     = (p == 0) ? thm[j] : o;
        th[4 + j] = (p == 0) ? o : thm[j];
    }

    float expv[4];
    classifier_sim(th, expv);

    float logits[10];
#pragma unroll
    for (int k = 0; k < 10; ++k) {
        float acc = bias[k];
#pragma unroll
        for (int j = 0; j < 4; ++j) acc += expv[j] * W[k * 4 + j];
        logits[k] = acc;
    }
    float m = logits[0];
#pragma unroll
    for (int k = 1; k < 10; ++k) m = fmaxf(m, logits[k]);
    float sum = 0.0f;
#pragma unroll
    for (int k = 0; k < 10; ++k) sum += __expf(logits[k] - m);
    const float lse = m + __logf(sum);

    // lane p writes outputs [5p, 5p+5)
    float* o = out + (size_t)b * 10 + p * 5;
#pragma unroll
    for (int k = 0; k < 5; ++k) o[k] = logits[p * 5 + k] - lse;
}

extern "C" void kernel_launch(void* const* d_in, const int* in_sizes, int n_in,
                              void* d_out, int out_size, void* d_ws, size_t ws_size,
                              hipStream_t stream) {
    const float* x    = (const float*)d_in[0];   // (B,28,28)
    const float* qp   = (const float*)d_in[1];   // (6,)
    const float* W    = (const float*)d_in[2];   // (10,4)
    const float* bias = (const float*)d_in[3];   // (10,)
    float* out = (float*)d_out;                  // (B,10)

    const int B = in_sizes[0] / 784;
    const int block = 256;
    const int grid = (2 * B + block - 1) / block;
    quanv_hybrid_kernel<<<grid, block, 0, stream>>>(x, qp, W, bias, out, B);
}